// Round 11
// baseline (475.599 us; speedup 1.0000x reference)
//
#include <hip/hip_runtime.h>

constexpr int NN  = 20000;   // nodes
constexpr int NE  = 320000;  // edges
constexpr int NG  = 64;      // graphs

typedef _Float16 f16x8v __attribute__((ext_vector_type(8)));
typedef float    f32x4v __attribute__((ext_vector_type(4)));

// workspace layout (in 4-byte units)
constexpr size_t OFF_B1C    = 16384;                      // 64 fp32
constexpr size_t OFF_B2C    = 81984;                      // 256 fp32
constexpr size_t OFF_AGGR1  = 82240;                      // 20000*64 fp32
constexpr size_t OFF_AGGR2  = 1362240;                    // 20000*256 fp32
constexpr size_t OFF_H1H    = 6482240;                    // 20000*256 f16
constexpr size_t OFF_BN1A   = 9042240;                    // n1w1 packed (K=64)
constexpr size_t OFF_BN1B   = 9050432;                    // n1w2 packed
constexpr size_t OFF_BN2A   = 9083200;                    // n2w1 packed
constexpr size_t OFF_BN2B   = 9115968;                    // n2w2 packed
constexpr size_t OFF_BPE    = 9148736;                    // ew1 packed (K=16 pad 32)
constexpr size_t OFF_XH     = 9152832;                    // x cast f16
constexpr size_t OFF_POOL   = 11602240;                   // 64*256
constexpr size_t OFF_CNT    = 11618624;                   // 64
constexpr size_t OFF_CURSOR = 11618688;                   // 20000 ints
constexpr size_t OFF_ROWPTR = 11638688;                   // 20001 ints
constexpr size_t OFF_PERM   = 11658689;                   // 320000 ints
constexpr size_t OFF_BP1    = 11978752;                   // f16 frag-packed W1c (fold)
constexpr size_t OFF_BP2    = 11986944;                   // f16 frag-packed W2c (fold)

// ---------------------------------------------------------------------------
// Shared MFMA 64-row GEMM: A = f16 LDS [64][KIN] swizzled, B = frag-packed.
// k-map on both sides: k = 32*s8 + 8*q + e.
// ---------------------------------------------------------------------------
template <int KIN, int NOUT>
__device__ __forceinline__ void mfma_gemm64(const _Float16* t_h,
                                            const _Float16* __restrict__ Bp,
                                            f32x4v (&acc)[4][NOUT / 64],
                                            int w, int lane) {
  const int q = lane >> 4, li = lane & 15;
  constexpr int KSTEPS = KIN / 32;
  constexpr int NTW = NOUT / 64;
  for (int s8 = 0; s8 < KSTEPS; ++s8) {
    f16x8v af[4];
#pragma unroll
    for (int m = 0; m < 4; ++m) {
      int r = 16 * m + li;
      int gl = 4 * s8 + q;
      af[m] = *(const f16x8v*)&t_h[r * KIN + ((gl ^ (r & 7)) << 3)];
    }
#pragma unroll
    for (int nl = 0; nl < NTW; ++nl) {
      int ng = w * NTW + nl;
      f16x8v bf = *(const f16x8v*)&Bp[(size_t)((ng * KSTEPS + s8) * 64 + lane) * 8];
#pragma unroll
      for (int m = 0; m < 4; ++m)
        acc[m][nl] = __builtin_amdgcn_mfma_f32_16x16x32_f16(af[m], bf, acc[m][nl], 0, 0, 0);
    }
  }
}

template <int NTW>
__device__ __forceinline__ void bias_init(f32x4v (&acc)[4][NTW],
                                          const float* __restrict__ b, int w, int li) {
#pragma unroll
  for (int nl = 0; nl < NTW; ++nl) {
    float bv = b[(w * NTW + nl) * 16 + li];
#pragma unroll
    for (int m = 0; m < 4; ++m) { f32x4v t = {bv, bv, bv, bv}; acc[m][nl] = t; }
  }
}

// ---------------------------------------------------------------------------
// prep_all: whole prep chain + degree count in one kernel.
// ---------------------------------------------------------------------------
__device__ __forceinline__ void pack_direct(const float* __restrict__ W,
                                            _Float16* __restrict__ Bp,
                                            int t, int ksteps, int nout, int kreal) {
  int lane = t & 63;
  int s = (t >> 6) % ksteps;
  int ng = t / (64 * ksteps);
  int kbase = 32 * s + 8 * (lane >> 4);
  int col = 16 * ng + (lane & 15);
  f16x8v v;
#pragma unroll
  for (int e = 0; e < 8; ++e)
    v[e] = (kbase + e < kreal) ? (_Float16)W[(size_t)(kbase + e) * nout + col]
                               : (_Float16)0.f;
  *(f16x8v*)&Bp[(size_t)t * 8] = v;
}

__device__ __forceinline__ void pack_fold(const float* __restrict__ ew2,
                                          const float* __restrict__ lew,
                                          _Float16* __restrict__ Bp,
                                          int t, int nout) {
  int lane = t & 63;
  int s = (t >> 6) & 7;                 // ksteps = 8
  int ng = t >> 9;
  int kbase = 32 * s + 8 * (lane >> 4);
  int col = 16 * ng + (lane & 15);
  f16x8v v;
#pragma unroll
  for (int e = 0; e < 8; ++e) {
    const float* wr = &ew2[(size_t)(kbase + e) * 256];
    float sacc = 0.f;
    for (int k2 = 0; k2 < 256; ++k2) sacc = fmaf(wr[k2], lew[(size_t)k2 * nout + col], sacc);
    v[e] = (_Float16)sacc;
  }
  *(f16x8v*)&Bp[(size_t)t * 8] = v;
}

constexpr int PR_XH   = 0;                 // 160000
constexpr int PR_BP1  = PR_XH + 160000;
constexpr int PR_BP2  = PR_BP1 + 2048;
constexpr int PR_N1A  = PR_BP2 + 8192;
constexpr int PR_N1B  = PR_N1A + 2048;
constexpr int PR_N2A  = PR_N1B + 8192;
constexpr int PR_N2B  = PR_N2A + 8192;
constexpr int PR_BPE  = PR_N2B + 8192;
constexpr int PR_B1C  = PR_BPE + 1024;
constexpr int PR_B2C  = PR_B1C + 64;
constexpr int PR_CNT  = PR_B2C + 256;
constexpr int PR_DEG  = PR_CNT + 64;
constexpr int PR_END  = PR_DEG + NE;       // degree count folded in

__global__ __launch_bounds__(256) void prep_all(
    const float* __restrict__ ew1, const float* __restrict__ eb1,
    const float* __restrict__ ew2, const float* __restrict__ eb2,
    const float* __restrict__ le1w, const float* __restrict__ le1b,
    const float* __restrict__ le2w, const float* __restrict__ le2b,
    const float* __restrict__ n1w1, const float* __restrict__ n1w2,
    const float* __restrict__ n2w1, const float* __restrict__ n2w2,
    const float* __restrict__ x, const int* __restrict__ batch,
    const int* __restrict__ eidx,
    _Float16* __restrict__ Bp1, _Float16* __restrict__ Bp2,
    _Float16* __restrict__ BpN1a, _Float16* __restrict__ BpN1b,
    _Float16* __restrict__ BpN2a, _Float16* __restrict__ BpN2b,
    _Float16* __restrict__ Bpe,
    float* __restrict__ b1c, float* __restrict__ b2c,
    _Float16* __restrict__ xh, float* __restrict__ cnts,
    int* __restrict__ deg) {
  int idx = blockIdx.x * 256 + threadIdx.x;
  if (idx >= PR_END) return;
  if (idx >= PR_DEG) {
    int e = idx - PR_DEG;
    atomicAdd(&deg[eidx[NE + e]], 1);
  } else if (idx < PR_BP1) {
    int t = idx - PR_XH;
    float4 a = *(const float4*)&x[(size_t)t * 8];
    float4 b = *(const float4*)&x[(size_t)t * 8 + 4];
    f16x8v v;
    v[0] = (_Float16)a.x; v[1] = (_Float16)a.y; v[2] = (_Float16)a.z; v[3] = (_Float16)a.w;
    v[4] = (_Float16)b.x; v[5] = (_Float16)b.y; v[6] = (_Float16)b.z; v[7] = (_Float16)b.w;
    *(f16x8v*)&xh[(size_t)t * 8] = v;
  } else if (idx < PR_BP2) {
    pack_fold(ew2, le1w, Bp1, idx - PR_BP1, 64);
  } else if (idx < PR_N1A) {
    pack_fold(ew2, le2w, Bp2, idx - PR_BP2, 256);
  } else if (idx < PR_N1B) {
    pack_direct(n1w1, BpN1a, idx - PR_N1A, 2, 256, 64);
  } else if (idx < PR_N2A) {
    pack_direct(n1w2, BpN1b, idx - PR_N1B, 8, 256, 256);
  } else if (idx < PR_N2B) {
    pack_direct(n2w1, BpN2a, idx - PR_N2A, 8, 256, 256);
  } else if (idx < PR_BPE) {
    pack_direct(n2w2, BpN2b, idx - PR_N2B, 8, 256, 256);
  } else if (idx < PR_B1C) {
    pack_direct(ew1, Bpe, idx - PR_BPE, 1, 256, 16);
  } else if (idx < PR_B2C) {
    int j = idx - PR_B1C;
    float s = le1b[j];
    for (int k = 0; k < 256; ++k) s = fmaf(eb2[k], le1w[k * 64 + j], s);
    b1c[j] = s;
  } else if (idx < PR_CNT) {
    int j = idx - PR_B2C;
    float s = le2b[j];
    for (int k = 0; k < 256; ++k) s = fmaf(eb2[k], le2w[k * 256 + j], s);
    b2c[j] = s;
  } else {
    int g = idx - PR_CNT;
    int lo = 0, hi = NN;
    while (lo < hi) { int mid = (lo + hi) >> 1; if (batch[mid] < g) lo = mid + 1; else hi = mid; }
    int start = lo;
    lo = 0; hi = NN;
    while (lo < hi) { int mid = (lo + hi) >> 1; if (batch[mid] <= g) lo = mid + 1; else hi = mid; }
    cnts[g] = (float)(lo - start);
  }
}

// ----------------------- CSR build -------------------------
// Single-pass scan: thread t owns 20 contiguous elements; one wave scan +
// one cross-wave combine instead of 20 barrier-separated chunks.
__global__ __launch_bounds__(1024) void scan_rowptr(int* __restrict__ degcur,
                                                    int* __restrict__ rowptr) {
  __shared__ int wsum[16];
  const int tid = threadIdx.x, lane = tid & 63, w = tid >> 6;
  constexpr int PT = (NN + 1023) / 1024;   // 20
  const int base = tid * PT;
  int loc[PT];
  int s = 0;
#pragma unroll
  for (int i = 0; i < PT; ++i) {
    int idx = base + i;
    int v = (idx < NN) ? degcur[idx] : 0;
    loc[i] = s;
    s += v;
  }
  int x = s;
#pragma unroll
  for (int off = 1; off < 64; off <<= 1) {
    int y = __shfl_up(x, off, 64);
    if (lane >= off) x += y;
  }
  if (lane == 63) wsum[w] = x;
  __syncthreads();
  int woff = 0;
  for (int k = 0; k < w; ++k) woff += wsum[k];
  int total = 0;
  for (int k = 0; k < 16; ++k) total += wsum[k];
  const int ex = woff + x - s;             // exclusive prefix of this thread's chunk
#pragma unroll
  for (int i = 0; i < PT; ++i) {
    int idx = base + i;
    if (idx < NN) {
      int val = ex + loc[i];
      rowptr[idx] = val;
      degcur[idx] = val;                   // becomes scatter cursor
    }
  }
  if (tid == 0) rowptr[NN] = total;
}

__global__ __launch_bounds__(256) void scatter_perm(const int* __restrict__ eidx,
                                                    int* __restrict__ cursor,
                                                    int* __restrict__ perm) {
  int e = blockIdx.x * 256 + threadIdx.x;
  if (e < NE) {
    int d = eidx[NE + e];
    int slot = atomicAdd(&cursor[d], 1);
    perm[slot] = e;
  }
}

// ---------------------------------------------------------------------------
// MFMA edge conv, dst-sorted, sigma row permutation; MFMA t-phase.
// LDS = t_h only (32 KB) -> 5 blocks/CU. Edge meta (perm/src/dst) lives in
// registers (one edge per lane, per-wave copy) and crosses lanes via __shfl.
// ---------------------------------------------------------------------------
template <int NOUT>
__global__ __launch_bounds__(256, 5) void edge_conv_mfma(
    const float* __restrict__ edge_attr, const int* __restrict__ eidx,
    const int* __restrict__ perm,
    const _Float16* __restrict__ Bpe, const float* __restrict__ eb1,
    const _Float16* __restrict__ Bp, const float* __restrict__ bc,
    const _Float16* __restrict__ gat, float* __restrict__ aggr) {
  constexpr int NTW = NOUT / 64;
  constexpr int NG8 = NOUT / 8;
  __shared__ _Float16 t_h[64 * 256];     // exactly 32 KB
  const int tid = threadIdx.x;
  const int e0 = blockIdx.x * 64;
  const int lane = tid & 63, w = tid >> 6;
  const int q = lane >> 4, li = lane & 15;

  // per-lane edge meta (each wave loads a redundant full copy)
  const int p_r   = perm[e0 + lane];
  const int src_r = eidx[p_r];
  const int dst_r = eidx[NE + p_r];

  // t-phase: A-frags straight from global fp32 (cols 16-31 are zero-pad; the
  // q>=2 lanes hold exactly those columns -> keep zero vector, matches Bpe)
  f32x4v acct[4][4];
  bias_init<4>(acct, eb1, w, li);
  {
    f16x8v afe[4];
#pragma unroll
    for (int m = 0; m < 4; ++m) {
      int row = __shfl(p_r, 16 * m + li);   // all lanes participate
      f16x8v v = {};
      if (q < 2) {
        const float* sp = &edge_attr[(size_t)row * 16 + 8 * q];
        float4 a = *(const float4*)sp;
        float4 b = *(const float4*)(sp + 4);
        v[0] = (_Float16)a.x; v[1] = (_Float16)a.y; v[2] = (_Float16)a.z; v[3] = (_Float16)a.w;
        v[4] = (_Float16)b.x; v[5] = (_Float16)b.y; v[6] = (_Float16)b.z; v[7] = (_Float16)b.w;
      }
      afe[m] = v;
    }
#pragma unroll
    for (int nl = 0; nl < 4; ++nl) {
      f16x8v bf = *(const f16x8v*)&Bpe[(size_t)((w * 4 + nl) * 64 + lane) * 8];
#pragma unroll
      for (int m = 0; m < 4; ++m)
        acct[m][nl] = __builtin_amdgcn_mfma_f32_16x16x32_f16(afe[m], bf, acct[m][nl], 0, 0, 0);
    }
    // store t with sigma row-permutation + XOR swizzle (ReLU applied)
#pragma unroll
    for (int m = 0; m < 4; ++m)
#pragma unroll
      for (int nl = 0; nl < 4; ++nl)
#pragma unroll
        for (int r = 0; r < 4; ++r) {
          int E = 16 * m + 4 * q + r;                                   // edge = D row
          int p = (((E >> 2) & 3) << 4) | ((E >> 4) << 2) | (E & 3);    // sigma(E)
          int col = (w * 4 + nl) * 16 + li;
          int g = col >> 3;
          t_h[p * 256 + ((g ^ (p & 7)) << 3) + (col & 7)] =
              (_Float16)fmaxf(acct[m][nl][r], 0.f);
        }
  }

  f32x4v acc[4][NTW];
  bias_init<NTW>(acc, bc, w, li);
  __syncthreads();   // t_h visible to all waves

  for (int s8 = 0; s8 < 8; ++s8) {
    f16x8v af[4];
#pragma unroll
    for (int m = 0; m < 4; ++m) {
      int r = 16 * m + li;
      int gl = 4 * s8 + q;
      af[m] = *(const f16x8v*)&t_h[r * 256 + ((gl ^ (r & 7)) << 3)];
    }
#pragma unroll
    for (int nl = 0; nl < NTW; ++nl) {
      int ng = w * NTW + nl;
      f16x8v bf = *(const f16x8v*)&Bp[(size_t)((ng * 8 + s8) * 64 + lane) * 8];
#pragma unroll
      for (int m = 0; m < 4; ++m)
        acc[m][nl] = __builtin_amdgcn_mfma_f32_16x16x32_f16(af[m], bf, acc[m][nl], 0, 0, 0);
    }
  }
  __syncthreads();   // all t_h reads done; reuse as gather tile

  for (int c = tid; c < 64 * NG8; c += 256) {
    int e = c / NG8, g = c % NG8;
    int srcn = __shfl(src_r, e);
    f16x8v v = *(const f16x8v*)&gat[(size_t)srcn * NOUT + g * 8];
    int pg = (g & ~7) | ((g + 2 * (e >> 4)) & 7);
    *(f16x8v*)&t_h[e * NOUT + pg * 8] = v;
  }
  __syncthreads();

  // epilogue: lane owns edges [16q,16q+16); run-merged atomics (dst via shfl)
#pragma unroll
  for (int nl = 0; nl < NTW; ++nl) {
    const int col = (w * NTW + nl) * 16 + li;
    const int gl2 = col >> 3;
    const int pg = (gl2 & ~7) | ((gl2 + 2 * q) & 7);
    const int loff = pg * 8 + (col & 7);
    float run = 0.f;
    int cur = __shfl(dst_r, 16 * q);
#pragma unroll
    for (int m = 0; m < 4; ++m) {
#pragma unroll
      for (int r = 0; r < 4; ++r) {
        int e = 16 * q + 4 * m + r;
        int d = __shfl(dst_r, e);
        if (d != cur) {
          atomicAdd(&aggr[(size_t)cur * NOUT + col], run);
          run = 0.f; cur = d;
        }
        float xv = (float)t_h[e * NOUT + loff];
        run += fmaxf(xv + acc[m][nl][r], 0.f);
      }
    }
    atomicAdd(&aggr[(size_t)cur * NOUT + col], run);
  }
}

// ---------------------------------------------------------------------------
// MFMA node MLP 1
// ---------------------------------------------------------------------------
__global__ __launch_bounds__(256, 3) void node_mlp1_mfma(
    const float* __restrict__ x, const float* __restrict__ aggr1,
    const _Float16* __restrict__ BpA, const float* __restrict__ b1,
    const _Float16* __restrict__ BpB, const float* __restrict__ b2,
    _Float16* __restrict__ h1h) {
  __shared__ _Float16 t_h[64 * 256];
  const int tid = threadIdx.x;
  const int i0 = blockIdx.x * 64;
  const int lane = tid & 63, w = tid >> 6;
  const int q = lane >> 4, li = lane & 15;

#pragma unroll
  for (int r2 = 0; r2 < 2; ++r2) {
    int idx = tid + r2 * 256;
    int e = idx >> 3, g = idx & 7;
    int node = i0 + e;
    f16x8v v;
#pragma unroll
    for (int j = 0; j < 8; ++j) v[j] = (_Float16)0.f;
    if (node < NN) {
      float4 a0 = *(const float4*)&x[(size_t)node * 64 + g * 8];
      float4 a1 = *(const float4*)&x[(size_t)node * 64 + g * 8 + 4];
      float4 c0 = *(const float4*)&aggr1[(size_t)node * 64 + g * 8];
      float4 c1 = *(const float4*)&aggr1[(size_t)node * 64 + g * 8 + 4];
      v[0] = (_Float16)(a0.x + c0.x); v[1] = (_Float16)(a0.y + c0.y);
      v[2] = (_Float16)(a0.z + c0.z); v[3] = (_Float16)(a0.w + c0.w);
      v[4] = (_Float16)(a1.x + c1.x); v[5] = (_Float16)(a1.y + c1.y);
      v[6] = (_Float16)(a1.z + c1.z); v[7] = (_Float16)(a1.w + c1.w);
    }
    *(f16x8v*)&t_h[e * 64 + ((g ^ (e & 7)) << 3)] = v;
  }
  __syncthreads();

  f32x4v acc[4][4];
  bias_init<4>(acc, b1, w, li);
  mfma_gemm64<64, 256>(t_h, BpA, acc, w, lane);
  __syncthreads();

#pragma unroll
  for (int m = 0; m < 4; ++m)
#pragma unroll
    for (int nl = 0; nl < 4; ++nl)
#pragma unroll
      for (int r = 0; r < 4; ++r) {
        int row = 16 * m + 4 * q + r;
        int col = (w * 4 + nl) * 16 + li;
        int g = col >> 3;
        t_h[row * 256 + ((g ^ (row & 7)) << 3) + (col & 7)] =
            (_Float16)fmaxf(acc[m][nl][r], 0.f);
      }
  __syncthreads();

  bias_init<4>(acc, b2, w, li);
  mfma_gemm64<256, 256>(t_h, BpB, acc, w, lane);
  __syncthreads();

#pragma unroll
  for (int m = 0; m < 4; ++m)
#pragma unroll
    for (int nl = 0; nl < 4; ++nl)
#pragma unroll
      for (int r = 0; r < 4; ++r) {
        int row = 16 * m + 4 * q + r;
        int col = (w * 4 + nl) * 16 + li;
        t_h[row * 256 + col] = (_Float16)fmaxf(acc[m][nl][r], 0.f);
      }
  __syncthreads();

#pragma unroll
  for (int r8 = 0; r8 < 8; ++r8) {
    int idx = tid + r8 * 256;
    int e = idx >> 5, g = idx & 31;
    int node = i0 + e;
    if (node < NN)
      *(f16x8v*)&h1h[(size_t)node * 256 + g * 8] = *(const f16x8v*)&t_h[e * 256 + g * 8];
  }
}

// ---------------------------------------------------------------------------
// MFMA node MLP 2 + fused mean-pool numerator
// ---------------------------------------------------------------------------
__global__ __launch_bounds__(256, 3) void node_mlp2_mfma(
    const _Float16* __restrict__ h1h, const float* __restrict__ aggr2,
    const _Float16* __restrict__ BpA, const float* __restrict__ b1,
    const _Float16* __restrict__ BpB, const float* __restrict__ b2,
    const int* __restrict__ batch, float* __restrict__ pool) {
  __shared__ _Float16 t_h[64 * 256];
  __shared__ int batch_s[64];
  const int tid = threadIdx.x;
  const int i0 = blockIdx.x * 64;
  const int lane = tid & 63, w = tid >> 6;
  const int q = lane >> 4, li = lane & 15;

  if (tid < 64) batch_s[tid] = (i0 + tid < NN) ? batch[i0 + tid] : -1;

#pragma unroll
  for (int r8 = 0; r8 < 8; ++r8) {
    int idx = tid + r8 * 256;
    int e = idx >> 5, g = idx & 31;
    int node = i0 + e;
    f16x8v v;
#pragma unroll
    for (int j = 0; j < 8; ++j) v[j] = (_Float16)0.f;
    if (node < NN) {
      f16x8v a = *(const f16x8v*)&h1h[(size_t)node * 256 + g * 8];
      float4 c0 = *(const float4*)&aggr2[(size_t)node * 256 + g * 8];
      float4 c1 = *(const float4*)&aggr2[(size_t)node * 256 + g * 8 + 4];
      v[0] = (_Float16)((float)a[0] + c0.x); v[1] = (_Float16)((float)a[1] + c0.y);
      v[2] = (_Float16)((float)a[2] + c0.z); v[3] = (_Float16)((float)a[3] + c0.w);
      v[4] = (_Float16)((float)a[4] + c1.x); v[5] = (_Float16)((float)a[5] + c1.y);
      v[6] = (_Float16)((float)a[6] + c1.z); v[7] = (_Float16)((float)a[7] + c1.w);
    }
    *(f16x8v*)&t_h[e * 256 + ((g ^ (e & 7)) << 3)] = v;
  }
  __syncthreads();

  f32x4v acc[4][4];
  bias_init<4>(acc, b1, w, li);
  mfma_gemm64<256, 256>(t_h, BpA, acc, w, lane);
  __syncthreads();

#pragma unroll
  for (int m = 0; m < 4; ++m)
#pragma unroll
    for (int nl = 0; nl < 4; ++nl)
#pragma unroll
      for (int r = 0; r < 4; ++r) {
        int row = 16 * m + 4 * q + r;
        int col = (w * 4 + nl) * 16 + li;
        int g = col >> 3;
        t_h[row * 256 + ((g ^ (row & 7)) << 3) + (col & 7)] =
            (_Float16)fmaxf(acc[m][nl][r], 0.f);
      }
  __syncthreads();

  bias_init<4>(acc, b2, w, li);
  mfma_gemm64<256, 256>(t_h, BpB, acc, w, lane);
  __syncthreads();

#pragma unroll
  for (int m = 0; m < 4; ++m)
#pragma unroll
    for (int nl = 0; nl < 4; ++nl)
#pragma unroll
      for (int r = 0; r < 4; ++r) {
        int row = 16 * m + 4 * q + r;
        int col = (w * 4 + nl) * 16 + li;
        t_h[row * 256 + col] = (_Float16)fmaxf(acc[m][nl][r], 0.f);
      }
  __syncthreads();

  float run = 0.f;
  int curg = -2;
  for (int m = 0; m < 64; ++m) {
    int g = batch_s[m];
    if (g != curg) {
      if (curg >= 0) atomicAdd(&pool[curg * 256 + tid], run);
      run = 0.f; curg = g;
    }
    if (g >= 0) run += (float)t_h[m * 256 + tid];
  }
  if (curg >= 0) atomicAdd(&pool[curg * 256 + tid], run);
}

__global__ __launch_bounds__(128) void head_kernel(
    const float* __restrict__ pool, const float* __restrict__ counts,
    const float* __restrict__ l1w, const float* __restrict__ l1b,
    const float* __restrict__ l2w, const float* __restrict__ l2b,
    const float* __restrict__ hs_w, const float* __restrict__ hs_b,
    const float* __restrict__ hp_w, const float* __restrict__ hp_b,
    const float* __restrict__ hn_w, const float* __restrict__ hn_b,
    float* __restrict__ out) {
  const int g = blockIdx.x, tid = threadIdx.x;
  __shared__ float g_s[256], g1_s[128], g2_s[64];
  float cnt = fmaxf(counts[g], 1.0f);
  g_s[tid] = pool[g * 256 + tid] / cnt;
  g_s[tid + 128] = pool[g * 256 + tid + 128] / cnt;
  __syncthreads();
  float s = l1b[tid];
  for (int k = 0; k < 256; ++k) s = fmaf(g_s[k], l1w[k * 128 + tid], s);
  g1_s[tid] = fmaxf(s, 0.f);
  __syncthreads();
  if (tid < 64) {
    float s2 = l2b[tid];
    for (int k = 0; k < 128; ++k) s2 = fmaf(g1_s[k], l2w[k * 64 + tid], s2);
    g2_s[tid] = fmaxf(s2, 0.f);
  }
  __syncthreads();
  if (tid < 64) {
    float v = g2_s[tid];
    float a = v * hs_w[tid], b = v * hp_w[tid], c = v * hn_w[tid];
    for (int off = 32; off > 0; off >>= 1) {
      a += __shfl_down(a, off, 64);
      b += __shfl_down(b, off, 64);
      c += __shfl_down(c, off, 64);
    }
    if (tid == 0) {
      out[g]        = a + hs_b[0];
      out[64 + g]   = b + hp_b[0];
      out[128 + g]  = c + hn_b[0];
    }
  }
}

extern "C" void kernel_launch(void* const* d_in, const int* in_sizes, int n_in,
                              void* d_out, int out_size, void* d_ws, size_t ws_size,
                              hipStream_t stream) {
  (void)in_sizes; (void)n_in; (void)out_size; (void)ws_size;
  const float* x         = (const float*)d_in[0];
  const int*   eidx      = (const int*)d_in[1];
  const int*   batch     = (const int*)d_in[2];
  const float* edge_attr = (const float*)d_in[3];
  const float* ew1  = (const float*)d_in[4];
  const float* eb1  = (const float*)d_in[5];
  const float* ew2  = (const float*)d_in[6];
  const float* eb2  = (const float*)d_in[7];
  const float* le1w = (const float*)d_in[8];
  const float* le1b = (const float*)d_in[9];
  const float* le2w = (const float*)d_in[10];
  const float* le2b = (const float*)d_in[11];
  const float* n1w1 = (const float*)d_in[12];
  const float* n1b1 = (const float*)d_in[13];
  const float* n1w2 = (const float*)d_in[14];
  const float* n1b2 = (const float*)d_in[15];
  const float* n2w1 = (const float*)d_in[16];
  const float* n2b1 = (const float*)d_in[17];
  const float* n2w2 = (const float*)d_in[18];
  const float* n2b2 = (const float*)d_in[19];
  const float* l1w  = (const float*)d_in[20];
  const float* l1b  = (const float*)d_in[21];
  const float* l2w  = (const float*)d_in[22];
  const float* l2b  = (const float*)d_in[23];
  const float* hs_w = (const float*)d_in[24];
  const float* hs_b = (const float*)d_in[25];
  const float* hp_w = (const float*)d_in[26];
  const float* hp_b = (const float*)d_in[27];
  const float* hn_w = (const float*)d_in[28];
  const float* hn_b = (const float*)d_in[29];

  float* ws    = (float*)d_ws;
  float* b1c   = ws + OFF_B1C;
  float* b2c   = ws + OFF_B2C;
  float* aggr1 = ws + OFF_AGGR1;
  float* aggr2 = ws + OFF_AGGR2;
  _Float16* h1h = (_Float16*)(ws + OFF_H1H);
  _Float16* xh  = (_Float16*)(ws + OFF_XH);
  float* pool  = ws + OFF_POOL;
  float* cnts  = ws + OFF_CNT;
  int*   cursor= (int*)ws + OFF_CURSOR;
  int*   rowptr= (int*)ws + OFF_ROWPTR;
  int*   perm  = (int*)ws + OFF_PERM;
  _Float16* Bp1  = (_Float16*)(ws + OFF_BP1);
  _Float16* Bp2  = (_Float16*)(ws + OFF_BP2);
  _Float16* BpN1a = (_Float16*)(ws + OFF_BN1A);
  _Float16* BpN1b = (_Float16*)(ws + OFF_BN1B);
  _Float16* BpN2a = (_Float16*)(ws + OFF_BN2A);
  _Float16* BpN2b = (_Float16*)(ws + OFF_BN2B);
  _Float16* Bpe  = (_Float16*)(ws + OFF_BPE);
  float* out   = (float*)d_out;

  hipMemsetAsync(aggr1, 0, (size_t)NN * 64 * 4, stream);
  hipMemsetAsync(aggr2, 0, (size_t)NN * 256 * 4, stream);
  hipMemsetAsync(pool, 0, (size_t)NG * 256 * 4, stream);
  hipMemsetAsync(cursor, 0, (size_t)NN * 4, stream);

  prep_all<<<(PR_END + 255) / 256, 256, 0, stream>>>(
      ew1, eb1, ew2, eb2, le1w, le1b, le2w, le2b,
      n1w1, n1w2, n2w1, n2w2, x, batch, eidx,
      Bp1, Bp2, BpN1a, BpN1b, BpN2a, BpN2b, Bpe, b1c, b2c, xh, cnts, cursor);

  scan_rowptr<<<1, 1024, 0, stream>>>(cursor, rowptr);
  scatter_perm<<<(NE + 255) / 256, 256, 0, stream>>>(eidx, cursor, perm);

  edge_conv_mfma<64><<<NE / 64, 256, 0, stream>>>(edge_attr, eidx, perm, Bpe, eb1,
                                                  Bp1, b1c, xh, aggr1);
  node_mlp1_mfma<<<(NN + 63) / 64, 256, 0, stream>>>(x, aggr1, BpN1a, n1b1, BpN1b, n1b2, h1h);
  edge_conv_mfma<256><<<NE / 64, 256, 0, stream>>>(edge_attr, eidx, perm, Bpe, eb1,
                                                   Bp2, b2c, h1h, aggr2);
  node_mlp2_mfma<<<(NN + 63) / 64, 256, 0, stream>>>(h1h, aggr2, BpN2a, n2b1, BpN2b, n2b2,
                                                     batch, pool);
  head_kernel<<<NG, 128, 0, stream>>>(pool, cnts, l1w, l1b, l2w, l2b,
                                      hs_w, hs_b, hp_w, hp_b, hn_w, hn_b, out);
}

// Round 12
// 307.039 us; speedup vs baseline: 1.5490x; 1.5490x over previous
//
#include <hip/hip_runtime.h>

constexpr int NN  = 20000;   // nodes
constexpr int NE  = 320000;  // edges
constexpr int NG  = 64;      // graphs

typedef _Float16 f16x8v __attribute__((ext_vector_type(8)));
typedef float    f32x4v __attribute__((ext_vector_type(4)));

// workspace layout (in 4-byte units)
constexpr size_t OFF_B1C    = 16384;                      // 64 fp32
constexpr size_t OFF_B2C    = 81984;                      // 256 fp32
constexpr size_t OFF_AGGR1  = 82240;                      // 20000*64 fp32
constexpr size_t OFF_AGGR2  = 1362240;                    // 20000*256 fp32
constexpr size_t OFF_H1H    = 6482240;                    // 20000*256 f16
constexpr size_t OFF_BN1A   = 9042240;                    // n1w1 packed (K=64)
constexpr size_t OFF_BN1B   = 9050432;                    // n1w2 packed
constexpr size_t OFF_BN2A   = 9083200;                    // n2w1 packed
constexpr size_t OFF_BN2B   = 9115968;                    // n2w2 packed
constexpr size_t OFF_BPE    = 9148736;                    // ew1 packed (K=16 pad 32)
constexpr size_t OFF_XH     = 9152832;                    // x cast f16
constexpr size_t OFF_POOL   = 11602240;                   // 64*256
constexpr size_t OFF_CNT    = 11618624;                   // 64
constexpr size_t OFF_CURSOR = 11618688;                   // 20000 ints
constexpr size_t OFF_ROWPTR = 11638688;                   // 20001 ints
constexpr size_t OFF_PERM   = 11658689;                   // 320000 ints
constexpr size_t OFF_BP1    = 11978752;                   // f16 frag-packed W1c (fold)
constexpr size_t OFF_BP2    = 11986944;                   // f16 frag-packed W2c (fold)

// ---------------------------------------------------------------------------
// Shared MFMA 64-row GEMM: A = f16 LDS [64][KIN] swizzled, B = frag-packed.
// k-map on both sides: k = 32*s8 + 8*q + e.
// ---------------------------------------------------------------------------
template <int KIN, int NOUT>
__device__ __forceinline__ void mfma_gemm64(const _Float16* t_h,
                                            const _Float16* __restrict__ Bp,
                                            f32x4v (&acc)[4][NOUT / 64],
                                            int w, int lane) {
  const int q = lane >> 4, li = lane & 15;
  constexpr int KSTEPS = KIN / 32;
  constexpr int NTW = NOUT / 64;
  for (int s8 = 0; s8 < KSTEPS; ++s8) {
    f16x8v af[4];
#pragma unroll
    for (int m = 0; m < 4; ++m) {
      int r = 16 * m + li;
      int gl = 4 * s8 + q;
      af[m] = *(const f16x8v*)&t_h[r * KIN + ((gl ^ (r & 7)) << 3)];
    }
#pragma unroll
    for (int nl = 0; nl < NTW; ++nl) {
      int ng = w * NTW + nl;
      f16x8v bf = *(const f16x8v*)&Bp[(size_t)((ng * KSTEPS + s8) * 64 + lane) * 8];
#pragma unroll
      for (int m = 0; m < 4; ++m)
        acc[m][nl] = __builtin_amdgcn_mfma_f32_16x16x32_f16(af[m], bf, acc[m][nl], 0, 0, 0);
    }
  }
}

template <int NTW>
__device__ __forceinline__ void bias_init(f32x4v (&acc)[4][NTW],
                                          const float* __restrict__ b, int w, int li) {
#pragma unroll
  for (int nl = 0; nl < NTW; ++nl) {
    float bv = b[(w * NTW + nl) * 16 + li];
#pragma unroll
    for (int m = 0; m < 4; ++m) { f32x4v t = {bv, bv, bv, bv}; acc[m][nl] = t; }
  }
}

// ---------------------------------------------------------------------------
// prep_all: whole prep chain + degree count in one kernel.
// ---------------------------------------------------------------------------
__device__ __forceinline__ void pack_direct(const float* __restrict__ W,
                                            _Float16* __restrict__ Bp,
                                            int t, int ksteps, int nout, int kreal) {
  int lane = t & 63;
  int s = (t >> 6) % ksteps;
  int ng = t / (64 * ksteps);
  int kbase = 32 * s + 8 * (lane >> 4);
  int col = 16 * ng + (lane & 15);
  f16x8v v;
#pragma unroll
  for (int e = 0; e < 8; ++e)
    v[e] = (kbase + e < kreal) ? (_Float16)W[(size_t)(kbase + e) * nout + col]
                               : (_Float16)0.f;
  *(f16x8v*)&Bp[(size_t)t * 8] = v;
}

__device__ __forceinline__ void pack_fold(const float* __restrict__ ew2,
                                          const float* __restrict__ lew,
                                          _Float16* __restrict__ Bp,
                                          int t, int nout) {
  int lane = t & 63;
  int s = (t >> 6) & 7;                 // ksteps = 8
  int ng = t >> 9;
  int kbase = 32 * s + 8 * (lane >> 4);
  int col = 16 * ng + (lane & 15);
  f16x8v v;
#pragma unroll
  for (int e = 0; e < 8; ++e) {
    const float* wr = &ew2[(size_t)(kbase + e) * 256];
    float sacc = 0.f;
    for (int k2 = 0; k2 < 256; ++k2) sacc = fmaf(wr[k2], lew[(size_t)k2 * nout + col], sacc);
    v[e] = (_Float16)sacc;
  }
  *(f16x8v*)&Bp[(size_t)t * 8] = v;
}

constexpr int PR_XH   = 0;                 // 160000
constexpr int PR_BP1  = PR_XH + 160000;
constexpr int PR_BP2  = PR_BP1 + 2048;
constexpr int PR_N1A  = PR_BP2 + 8192;
constexpr int PR_N1B  = PR_N1A + 2048;
constexpr int PR_N2A  = PR_N1B + 8192;
constexpr int PR_N2B  = PR_N2A + 8192;
constexpr int PR_BPE  = PR_N2B + 8192;
constexpr int PR_B1C  = PR_BPE + 1024;
constexpr int PR_B2C  = PR_B1C + 64;
constexpr int PR_CNT  = PR_B2C + 256;
constexpr int PR_DEG  = PR_CNT + 64;
constexpr int PR_END  = PR_DEG + NE;       // degree count folded in

__global__ __launch_bounds__(256) void prep_all(
    const float* __restrict__ ew1, const float* __restrict__ eb1,
    const float* __restrict__ ew2, const float* __restrict__ eb2,
    const float* __restrict__ le1w, const float* __restrict__ le1b,
    const float* __restrict__ le2w, const float* __restrict__ le2b,
    const float* __restrict__ n1w1, const float* __restrict__ n1w2,
    const float* __restrict__ n2w1, const float* __restrict__ n2w2,
    const float* __restrict__ x, const int* __restrict__ batch,
    const int* __restrict__ eidx,
    _Float16* __restrict__ Bp1, _Float16* __restrict__ Bp2,
    _Float16* __restrict__ BpN1a, _Float16* __restrict__ BpN1b,
    _Float16* __restrict__ BpN2a, _Float16* __restrict__ BpN2b,
    _Float16* __restrict__ Bpe,
    float* __restrict__ b1c, float* __restrict__ b2c,
    _Float16* __restrict__ xh, float* __restrict__ cnts,
    int* __restrict__ deg) {
  int idx = blockIdx.x * 256 + threadIdx.x;
  if (idx >= PR_END) return;
  if (idx >= PR_DEG) {
    int e = idx - PR_DEG;
    atomicAdd(&deg[eidx[NE + e]], 1);
  } else if (idx < PR_BP1) {
    int t = idx - PR_XH;
    float4 a = *(const float4*)&x[(size_t)t * 8];
    float4 b = *(const float4*)&x[(size_t)t * 8 + 4];
    f16x8v v;
    v[0] = (_Float16)a.x; v[1] = (_Float16)a.y; v[2] = (_Float16)a.z; v[3] = (_Float16)a.w;
    v[4] = (_Float16)b.x; v[5] = (_Float16)b.y; v[6] = (_Float16)b.z; v[7] = (_Float16)b.w;
    *(f16x8v*)&xh[(size_t)t * 8] = v;
  } else if (idx < PR_BP2) {
    pack_fold(ew2, le1w, Bp1, idx - PR_BP1, 64);
  } else if (idx < PR_N1A) {
    pack_fold(ew2, le2w, Bp2, idx - PR_BP2, 256);
  } else if (idx < PR_N1B) {
    pack_direct(n1w1, BpN1a, idx - PR_N1A, 2, 256, 64);
  } else if (idx < PR_N2A) {
    pack_direct(n1w2, BpN1b, idx - PR_N1B, 8, 256, 256);
  } else if (idx < PR_N2B) {
    pack_direct(n2w1, BpN2a, idx - PR_N2A, 8, 256, 256);
  } else if (idx < PR_BPE) {
    pack_direct(n2w2, BpN2b, idx - PR_N2B, 8, 256, 256);
  } else if (idx < PR_B1C) {
    pack_direct(ew1, Bpe, idx - PR_BPE, 1, 256, 16);
  } else if (idx < PR_B2C) {
    int j = idx - PR_B1C;
    float s = le1b[j];
    for (int k = 0; k < 256; ++k) s = fmaf(eb2[k], le1w[k * 64 + j], s);
    b1c[j] = s;
  } else if (idx < PR_CNT) {
    int j = idx - PR_B2C;
    float s = le2b[j];
    for (int k = 0; k < 256; ++k) s = fmaf(eb2[k], le2w[k * 256 + j], s);
    b2c[j] = s;
  } else {
    int g = idx - PR_CNT;
    int lo = 0, hi = NN;
    while (lo < hi) { int mid = (lo + hi) >> 1; if (batch[mid] < g) lo = mid + 1; else hi = mid; }
    int start = lo;
    lo = 0; hi = NN;
    while (lo < hi) { int mid = (lo + hi) >> 1; if (batch[mid] <= g) lo = mid + 1; else hi = mid; }
    cnts[g] = (float)(lo - start);
  }
}

// ----------------------- CSR build -------------------------
// Single-pass scan: thread t owns 20 contiguous elements.
__global__ __launch_bounds__(1024) void scan_rowptr(int* __restrict__ degcur,
                                                    int* __restrict__ rowptr) {
  __shared__ int wsum[16];
  const int tid = threadIdx.x, lane = tid & 63, w = tid >> 6;
  constexpr int PT = (NN + 1023) / 1024;   // 20
  const int base = tid * PT;
  int loc[PT];
  int s = 0;
#pragma unroll
  for (int i = 0; i < PT; ++i) {
    int idx = base + i;
    int v = (idx < NN) ? degcur[idx] : 0;
    loc[i] = s;
    s += v;
  }
  int x = s;
#pragma unroll
  for (int off = 1; off < 64; off <<= 1) {
    int y = __shfl_up(x, off, 64);
    if (lane >= off) x += y;
  }
  if (lane == 63) wsum[w] = x;
  __syncthreads();
  int woff = 0;
  for (int k = 0; k < w; ++k) woff += wsum[k];
  int total = 0;
  for (int k = 0; k < 16; ++k) total += wsum[k];
  const int ex = woff + x - s;
#pragma unroll
  for (int i = 0; i < PT; ++i) {
    int idx = base + i;
    if (idx < NN) {
      int val = ex + loc[i];
      rowptr[idx] = val;
      degcur[idx] = val;                   // becomes scatter cursor
    }
  }
  if (tid == 0) rowptr[NN] = total;
}

__global__ __launch_bounds__(256) void scatter_perm(const int* __restrict__ eidx,
                                                    int* __restrict__ cursor,
                                                    int* __restrict__ perm) {
  int e = blockIdx.x * 256 + threadIdx.x;
  if (e < NE) {
    int d = eidx[NE + e];
    int slot = atomicAdd(&cursor[d], 1);
    perm[slot] = e;
  }
}

// ---------------------------------------------------------------------------
// MFMA edge conv (R10 proven form): ea_h LDS staging, meta in LDS, (256,4).
// NOTE R11 lesson: forcing 5 blocks/CU via launch_bounds spills the MFMA
// accumulators to scratch (VGPR 64->48, WRITE +565MB) — do not raise.
// ---------------------------------------------------------------------------
template <int NOUT>
__global__ __launch_bounds__(256, 4) void edge_conv_mfma(
    const float* __restrict__ edge_attr, const int* __restrict__ eidx,
    const int* __restrict__ perm,
    const _Float16* __restrict__ Bpe, const float* __restrict__ eb1,
    const _Float16* __restrict__ Bp, const float* __restrict__ bc,
    const _Float16* __restrict__ gat, float* __restrict__ aggr) {
  constexpr int NTW = NOUT / 64;
  constexpr int NG8 = NOUT / 8;
  __shared__ _Float16 ea_h[64 * 40];
  __shared__ _Float16 t_h[64 * 256];
  __shared__ int perm_s[64], src_s[64], dst_s[64];
  const int tid = threadIdx.x;
  const int e0 = blockIdx.x * 64;
  const int lane = tid & 63, w = tid >> 6;
  const int q = lane >> 4, li = lane & 15;

  if (tid < 64) {
    int p = perm[e0 + tid];
    perm_s[tid] = p;
    src_s[tid] = eidx[p];
    dst_s[tid] = eidx[NE + p];
  }
  __syncthreads();
  {
    int e2 = (tid & 127) >> 1, gq = tid & 1;
    if (tid < 128) {
      const float* src = &edge_attr[(size_t)perm_s[e2] * 16 + gq * 8];
      float4 a = *(const float4*)src;
      float4 b = *(const float4*)(src + 4);
      f16x8v v;
      v[0] = (_Float16)a.x; v[1] = (_Float16)a.y; v[2] = (_Float16)a.z; v[3] = (_Float16)a.w;
      v[4] = (_Float16)b.x; v[5] = (_Float16)b.y; v[6] = (_Float16)b.z; v[7] = (_Float16)b.w;
      *(f16x8v*)&ea_h[e2 * 40 + gq * 8] = v;
    } else {
      f16x8v z = {};
      *(f16x8v*)&ea_h[e2 * 40 + 16 + gq * 8] = z;   // zero pad k=16..31
    }
  }

  f32x4v acct[4][4];
  bias_init<4>(acct, eb1, w, li);
  __syncthreads();
  {
    f16x8v afe[4];
#pragma unroll
    for (int m = 0; m < 4; ++m)
      afe[m] = *(const f16x8v*)&ea_h[(16 * m + li) * 40 + 8 * q];
#pragma unroll
    for (int nl = 0; nl < 4; ++nl) {
      f16x8v bf = *(const f16x8v*)&Bpe[(size_t)((w * 4 + nl) * 64 + lane) * 8];
#pragma unroll
      for (int m = 0; m < 4; ++m)
        acct[m][nl] = __builtin_amdgcn_mfma_f32_16x16x32_f16(afe[m], bf, acct[m][nl], 0, 0, 0);
    }
#pragma unroll
    for (int m = 0; m < 4; ++m)
#pragma unroll
      for (int nl = 0; nl < 4; ++nl)
#pragma unroll
        for (int r = 0; r < 4; ++r) {
          int E = 16 * m + 4 * q + r;                                   // edge = D row
          int p = (((E >> 2) & 3) << 4) | ((E >> 4) << 2) | (E & 3);    // sigma(E)
          int col = (w * 4 + nl) * 16 + li;
          int g = col >> 3;
          t_h[p * 256 + ((g ^ (p & 7)) << 3) + (col & 7)] =
              (_Float16)fmaxf(acct[m][nl][r], 0.f);
        }
  }

  f32x4v acc[4][NTW];
  bias_init<NTW>(acc, bc, w, li);
  __syncthreads();

  for (int s8 = 0; s8 < 8; ++s8) {
    f16x8v af[4];
#pragma unroll
    for (int m = 0; m < 4; ++m) {
      int r = 16 * m + li;
      int gl = 4 * s8 + q;
      af[m] = *(const f16x8v*)&t_h[r * 256 + ((gl ^ (r & 7)) << 3)];
    }
#pragma unroll
    for (int nl = 0; nl < NTW; ++nl) {
      int ng = w * NTW + nl;
      f16x8v bf = *(const f16x8v*)&Bp[(size_t)((ng * 8 + s8) * 64 + lane) * 8];
#pragma unroll
      for (int m = 0; m < 4; ++m)
        acc[m][nl] = __builtin_amdgcn_mfma_f32_16x16x32_f16(af[m], bf, acc[m][nl], 0, 0, 0);
    }
  }
  __syncthreads();

  for (int c = tid; c < 64 * NG8; c += 256) {
    int e = c / NG8, g = c % NG8;
    f16x8v v = *(const f16x8v*)&gat[(size_t)src_s[e] * NOUT + g * 8];
    int pg = (g & ~7) | ((g + 2 * (e >> 4)) & 7);
    *(f16x8v*)&t_h[e * NOUT + pg * 8] = v;
  }
  __syncthreads();

#pragma unroll
  for (int nl = 0; nl < NTW; ++nl) {
    const int col = (w * NTW + nl) * 16 + li;
    const int gl2 = col >> 3;
    const int pg = (gl2 & ~7) | ((gl2 + 2 * q) & 7);
    const int loff = pg * 8 + (col & 7);
    float run = 0.f;
    int cur = dst_s[16 * q];
#pragma unroll
    for (int m = 0; m < 4; ++m) {
#pragma unroll
      for (int r = 0; r < 4; ++r) {
        int e = 16 * q + 4 * m + r;
        int d = dst_s[e];
        if (d != cur) {
          atomicAdd(&aggr[(size_t)cur * NOUT + col], run);
          run = 0.f; cur = d;
        }
        float xv = (float)t_h[e * NOUT + loff];
        run += fmaxf(xv + acc[m][nl][r], 0.f);
      }
    }
    atomicAdd(&aggr[(size_t)cur * NOUT + col], run);
  }
}

// ---------------------------------------------------------------------------
// MFMA node MLP 1
// ---------------------------------------------------------------------------
__global__ __launch_bounds__(256, 3) void node_mlp1_mfma(
    const float* __restrict__ x, const float* __restrict__ aggr1,
    const _Float16* __restrict__ BpA, const float* __restrict__ b1,
    const _Float16* __restrict__ BpB, const float* __restrict__ b2,
    _Float16* __restrict__ h1h) {
  __shared__ _Float16 t_h[64 * 256];
  const int tid = threadIdx.x;
  const int i0 = blockIdx.x * 64;
  const int lane = tid & 63, w = tid >> 6;
  const int q = lane >> 4, li = lane & 15;

#pragma unroll
  for (int r2 = 0; r2 < 2; ++r2) {
    int idx = tid + r2 * 256;
    int e = idx >> 3, g = idx & 7;
    int node = i0 + e;
    f16x8v v;
#pragma unroll
    for (int j = 0; j < 8; ++j) v[j] = (_Float16)0.f;
    if (node < NN) {
      float4 a0 = *(const float4*)&x[(size_t)node * 64 + g * 8];
      float4 a1 = *(const float4*)&x[(size_t)node * 64 + g * 8 + 4];
      float4 c0 = *(const float4*)&aggr1[(size_t)node * 64 + g * 8];
      float4 c1 = *(const float4*)&aggr1[(size_t)node * 64 + g * 8 + 4];
      v[0] = (_Float16)(a0.x + c0.x); v[1] = (_Float16)(a0.y + c0.y);
      v[2] = (_Float16)(a0.z + c0.z); v[3] = (_Float16)(a0.w + c0.w);
      v[4] = (_Float16)(a1.x + c1.x); v[5] = (_Float16)(a1.y + c1.y);
      v[6] = (_Float16)(a1.z + c1.z); v[7] = (_Float16)(a1.w + c1.w);
    }
    *(f16x8v*)&t_h[e * 64 + ((g ^ (e & 7)) << 3)] = v;
  }
  __syncthreads();

  f32x4v acc[4][4];
  bias_init<4>(acc, b1, w, li);
  mfma_gemm64<64, 256>(t_h, BpA, acc, w, lane);
  __syncthreads();

#pragma unroll
  for (int m = 0; m < 4; ++m)
#pragma unroll
    for (int nl = 0; nl < 4; ++nl)
#pragma unroll
      for (int r = 0; r < 4; ++r) {
        int row = 16 * m + 4 * q + r;
        int col = (w * 4 + nl) * 16 + li;
        int g = col >> 3;
        t_h[row * 256 + ((g ^ (row & 7)) << 3) + (col & 7)] =
            (_Float16)fmaxf(acc[m][nl][r], 0.f);
      }
  __syncthreads();

  bias_init<4>(acc, b2, w, li);
  mfma_gemm64<256, 256>(t_h, BpB, acc, w, lane);
  __syncthreads();

#pragma unroll
  for (int m = 0; m < 4; ++m)
#pragma unroll
    for (int nl = 0; nl < 4; ++nl)
#pragma unroll
      for (int r = 0; r < 4; ++r) {
        int row = 16 * m + 4 * q + r;
        int col = (w * 4 + nl) * 16 + li;
        t_h[row * 256 + col] = (_Float16)fmaxf(acc[m][nl][r], 0.f);
      }
  __syncthreads();

#pragma unroll
  for (int r8 = 0; r8 < 8; ++r8) {
    int idx = tid + r8 * 256;
    int e = idx >> 5, g = idx & 31;
    int node = i0 + e;
    if (node < NN)
      *(f16x8v*)&h1h[(size_t)node * 256 + g * 8] = *(const f16x8v*)&t_h[e * 256 + g * 8];
  }
}

// ---------------------------------------------------------------------------
// MFMA node MLP 2 + fused mean-pool numerator
// ---------------------------------------------------------------------------
__global__ __launch_bounds__(256, 3) void node_mlp2_mfma(
    const _Float16* __restrict__ h1h, const float* __restrict__ aggr2,
    const _Float16* __restrict__ BpA, const float* __restrict__ b1,
    const _Float16* __restrict__ BpB, const float* __restrict__ b2,
    const int* __restrict__ batch, float* __restrict__ pool) {
  __shared__ _Float16 t_h[64 * 256];
  __shared__ int batch_s[64];
  const int tid = threadIdx.x;
  const int i0 = blockIdx.x * 64;
  const int lane = tid & 63, w = tid >> 6;
  const int q = lane >> 4, li = lane & 15;

  if (tid < 64) batch_s[tid] = (i0 + tid < NN) ? batch[i0 + tid] : -1;

#pragma unroll
  for (int r8 = 0; r8 < 8; ++r8) {
    int idx = tid + r8 * 256;
    int e = idx >> 5, g = idx & 31;
    int node = i0 + e;
    f16x8v v;
#pragma unroll
    for (int j = 0; j < 8; ++j) v[j] = (_Float16)0.f;
    if (node < NN) {
      f16x8v a = *(const f16x8v*)&h1h[(size_t)node * 256 + g * 8];
      float4 c0 = *(const float4*)&aggr2[(size_t)node * 256 + g * 8];
      float4 c1 = *(const float4*)&aggr2[(size_t)node * 256 + g * 8 + 4];
      v[0] = (_Float16)((float)a[0] + c0.x); v[1] = (_Float16)((float)a[1] + c0.y);
      v[2] = (_Float16)((float)a[2] + c0.z); v[3] = (_Float16)((float)a[3] + c0.w);
      v[4] = (_Float16)((float)a[4] + c1.x); v[5] = (_Float16)((float)a[5] + c1.y);
      v[6] = (_Float16)((float)a[6] + c1.z); v[7] = (_Float16)((float)a[7] + c1.w);
    }
    *(f16x8v*)&t_h[e * 256 + ((g ^ (e & 7)) << 3)] = v;
  }
  __syncthreads();

  f32x4v acc[4][4];
  bias_init<4>(acc, b1, w, li);
  mfma_gemm64<256, 256>(t_h, BpA, acc, w, lane);
  __syncthreads();

#pragma unroll
  for (int m = 0; m < 4; ++m)
#pragma unroll
    for (int nl = 0; nl < 4; ++nl)
#pragma unroll
      for (int r = 0; r < 4; ++r) {
        int row = 16 * m + 4 * q + r;
        int col = (w * 4 + nl) * 16 + li;
        int g = col >> 3;
        t_h[row * 256 + ((g ^ (row & 7)) << 3) + (col & 7)] =
            (_Float16)fmaxf(acc[m][nl][r], 0.f);
      }
  __syncthreads();

  bias_init<4>(acc, b2, w, li);
  mfma_gemm64<256, 256>(t_h, BpB, acc, w, lane);
  __syncthreads();

#pragma unroll
  for (int m = 0; m < 4; ++m)
#pragma unroll
    for (int nl = 0; nl < 4; ++nl)
#pragma unroll
      for (int r = 0; r < 4; ++r) {
        int row = 16 * m + 4 * q + r;
        int col = (w * 4 + nl) * 16 + li;
        t_h[row * 256 + col] = (_Float16)fmaxf(acc[m][nl][r], 0.f);
      }
  __syncthreads();

  float run = 0.f;
  int curg = -2;
  for (int m = 0; m < 64; ++m) {
    int g = batch_s[m];
    if (g != curg) {
      if (curg >= 0) atomicAdd(&pool[curg * 256 + tid], run);
      run = 0.f; curg = g;
    }
    if (g >= 0) run += (float)t_h[m * 256 + tid];
  }
  if (curg >= 0) atomicAdd(&pool[curg * 256 + tid], run);
}

__global__ __launch_bounds__(128) void head_kernel(
    const float* __restrict__ pool, const float* __restrict__ counts,
    const float* __restrict__ l1w, const float* __restrict__ l1b,
    const float* __restrict__ l2w, const float* __restrict__ l2b,
    const float* __restrict__ hs_w, const float* __restrict__ hs_b,
    const float* __restrict__ hp_w, const float* __restrict__ hp_b,
    const float* __restrict__ hn_w, const float* __restrict__ hn_b,
    float* __restrict__ out) {
  const int g = blockIdx.x, tid = threadIdx.x;
  __shared__ float g_s[256], g1_s[128], g2_s[64];
  float cnt = fmaxf(counts[g], 1.0f);
  g_s[tid] = pool[g * 256 + tid] / cnt;
  g_s[tid + 128] = pool[g * 256 + tid + 128] / cnt;
  __syncthreads();
  float s = l1b[tid];
  for (int k = 0; k < 256; ++k) s = fmaf(g_s[k], l1w[k * 128 + tid], s);
  g1_s[tid] = fmaxf(s, 0.f);
  __syncthreads();
  if (tid < 64) {
    float s2 = l2b[tid];
    for (int k = 0; k < 128; ++k) s2 = fmaf(g1_s[k], l2w[k * 64 + tid], s2);
    g2_s[tid] = fmaxf(s2, 0.f);
  }
  __syncthreads();
  if (tid < 64) {
    float v = g2_s[tid];
    float a = v * hs_w[tid], b = v * hp_w[tid], c = v * hn_w[tid];
    for (int off = 32; off > 0; off >>= 1) {
      a += __shfl_down(a, off, 64);
      b += __shfl_down(b, off, 64);
      c += __shfl_down(c, off, 64);
    }
    if (tid == 0) {
      out[g]        = a + hs_b[0];
      out[64 + g]   = b + hp_b[0];
      out[128 + g]  = c + hn_b[0];
    }
  }
}

extern "C" void kernel_launch(void* const* d_in, const int* in_sizes, int n_in,
                              void* d_out, int out_size, void* d_ws, size_t ws_size,
                              hipStream_t stream) {
  (void)in_sizes; (void)n_in; (void)out_size; (void)ws_size;
  const float* x         = (const float*)d_in[0];
  const int*   eidx      = (const int*)d_in[1];
  const int*   batch     = (const int*)d_in[2];
  const float* edge_attr = (const float*)d_in[3];
  const float* ew1  = (const float*)d_in[4];
  const float* eb1  = (const float*)d_in[5];
  const float* ew2  = (const float*)d_in[6];
  const float* eb2  = (const float*)d_in[7];
  const float* le1w = (const float*)d_in[8];
  const float* le1b = (const float*)d_in[9];
  const float* le2w = (const float*)d_in[10];
  const float* le2b = (const float*)d_in[11];
  const float* n1w1 = (const float*)d_in[12];
  const float* n1b1 = (const float*)d_in[13];
  const float* n1w2 = (const float*)d_in[14];
  const float* n1b2 = (const float*)d_in[15];
  const float* n2w1 = (const float*)d_in[16];
  const float* n2b1 = (const float*)d_in[17];
  const float* n2w2 = (const float*)d_in[18];
  const float* n2b2 = (const float*)d_in[19];
  const float* l1w  = (const float*)d_in[20];
  const float* l1b  = (const float*)d_in[21];
  const float* l2w  = (const float*)d_in[22];
  const float* l2b  = (const float*)d_in[23];
  const float* hs_w = (const float*)d_in[24];
  const float* hs_b = (const float*)d_in[25];
  const float* hp_w = (const float*)d_in[26];
  const float* hp_b = (const float*)d_in[27];
  const float* hn_w = (const float*)d_in[28];
  const float* hn_b = (const float*)d_in[29];

  float* ws    = (float*)d_ws;
  float* b1c   = ws + OFF_B1C;
  float* b2c   = ws + OFF_B2C;
  float* aggr1 = ws + OFF_AGGR1;
  float* aggr2 = ws + OFF_AGGR2;
  _Float16* h1h = (_Float16*)(ws + OFF_H1H);
  _Float16* xh  = (_Float16*)(ws + OFF_XH);
  float* pool  = ws + OFF_POOL;
  float* cnts  = ws + OFF_CNT;
  int*   cursor= (int*)ws + OFF_CURSOR;
  int*   rowptr= (int*)ws + OFF_ROWPTR;
  int*   perm  = (int*)ws + OFF_PERM;
  _Float16* Bp1  = (_Float16*)(ws + OFF_BP1);
  _Float16* Bp2  = (_Float16*)(ws + OFF_BP2);
  _Float16* BpN1a = (_Float16*)(ws + OFF_BN1A);
  _Float16* BpN1b = (_Float16*)(ws + OFF_BN1B);
  _Float16* BpN2a = (_Float16*)(ws + OFF_BN2A);
  _Float16* BpN2b = (_Float16*)(ws + OFF_BN2B);
  _Float16* Bpe  = (_Float16*)(ws + OFF_BPE);
  float* out   = (float*)d_out;

  hipMemsetAsync(aggr1, 0, (size_t)NN * 64 * 4, stream);
  hipMemsetAsync(aggr2, 0, (size_t)NN * 256 * 4, stream);
  hipMemsetAsync(pool, 0, (size_t)NG * 256 * 4, stream);
  hipMemsetAsync(cursor, 0, (size_t)NN * 4, stream);

  prep_all<<<(PR_END + 255) / 256, 256, 0, stream>>>(
      ew1, eb1, ew2, eb2, le1w, le1b, le2w, le2b,
      n1w1, n1w2, n2w1, n2w2, x, batch, eidx,
      Bp1, Bp2, BpN1a, BpN1b, BpN2a, BpN2b, Bpe, b1c, b2c, xh, cnts, cursor);

  scan_rowptr<<<1, 1024, 0, stream>>>(cursor, rowptr);
  scatter_perm<<<(NE + 255) / 256, 256, 0, stream>>>(eidx, cursor, perm);

  edge_conv_mfma<64><<<NE / 64, 256, 0, stream>>>(edge_attr, eidx, perm, Bpe, eb1,
                                                  Bp1, b1c, xh, aggr1);
  node_mlp1_mfma<<<(NN + 63) / 64, 256, 0, stream>>>(x, aggr1, BpN1a, n1b1, BpN1b, n1b2, h1h);
  edge_conv_mfma<256><<<NE / 64, 256, 0, stream>>>(edge_attr, eidx, perm, Bpe, eb1,
                                                   Bp2, b2c, h1h, aggr2);
  node_mlp2_mfma<<<(NN + 63) / 64, 256, 0, stream>>>(h1h, aggr2, BpN2a, n2b1, BpN2b, n2b2,
                                                     batch, pool);
  head_kernel<<<NG, 128, 0, stream>>>(pool, cnts, l1w, l1b, l2w, l2b,
                                      hs_w, hs_b, hp_w, hp_b, hn_w, hn_b, out);
}